// Round 1
// baseline (309.818 us; speedup 1.0000x reference)
//
#include <hip/hip_runtime.h>
#include <math.h>

#define BSZ 8
#define MROWS 64
#define NCOLS 4096
#define KSEL 32
#define EPSF 1e-20f
#define NEG_INF (-3.402823466e+38f)

typedef float floatx4 __attribute__((ext_vector_type(4)));

// ---------------------------------------------------------------------------
// Kernel 1: per-(b,m)-row top-32 selection. One block per row (512 blocks).
//   Phase A: all 4 waves stage perturbed row into swizzled LDS.
//   Phase B: wave 0 runs the proven barrier-free iterative top-32 + rank,
//            writes the 32 ascending-sorted winner indices to d_ws.
//   Waves 1-3 exit after staging (no barriers after the one syncthreads).
//
// Swizzle: column col lives at (col & ~63) | ((col + (col>>6)) & 63).
// Lane l owns chunk [64l, 64l+64). Per-lane chunk scan and all-lanes
// single-chunk rescan are both 2-lanes-per-bank (free on gfx950, m136).
// ---------------------------------------------------------------------------
__global__ __launch_bounds__(256) void topk_select_kernel(
    const float* __restrict__ logits,   // (64, 4096)
    const float* __restrict__ u,        // (8, 64, 4096)
    int* __restrict__ idx_out)          // (8*64, 32)
{
    __shared__ float vals[NCOLS];       // 16 KiB

    const int r   = blockIdx.x;         // row = b*64 + m
    const int m   = r & (MROWS - 1);
    const int tid = threadIdx.x;

    const float4* u4 = (const float4*)(u + (size_t)r * NCOLS);
    const float4* l4 = (const float4*)(logits + (size_t)m * NCOLS);

    // ---- Phase A: cooperative staging (256 threads x 4 float4) ----
    #pragma unroll
    for (int c = 0; c < 4; ++c) {
        int q = (c << 8) + tid;                  // float4 index, coalesced
        float4 uu = u4[q];
        float4 lg = l4[q];
        float px = lg.x - 0.001f * logf(-logf(uu.x + EPSF) + EPSF);
        float py = lg.y - 0.001f * logf(-logf(uu.y + EPSF) + EPSF);
        float pz = lg.z - 0.001f * logf(-logf(uu.z + EPSF) + EPSF);
        float pw = lg.w - 0.001f * logf(-logf(uu.w + EPSF) + EPSF);
        int col   = q << 2;
        int chunk = col >> 6;                    // same chunk for all 4 cols
        int base  = chunk << 6;
        vals[base + ((col + 0 + chunk) & 63)] = px;
        vals[base + ((col + 1 + chunk) & 63)] = py;
        vals[base + ((col + 2 + chunk) & 63)] = pz;
        vals[base + ((col + 3 + chunk) & 63)] = pw;
    }
    __syncthreads();

    const int lane = tid & 63;
    const int w    = tid >> 6;
    if (w != 0) return;                          // waves 1-3 done

    // ---- Phase B (wave 0): selection ----
    float lmax = NEG_INF;
    int   lidx = 0x7FFFFFFF;
    {
        const int cb = lane << 6;
        #pragma unroll 8
        for (int c = 0; c < 64; ++c) {           // ascending col => low-idx ties
            float v = vals[cb + ((c + lane) & 63)];
            if (v > lmax) { lmax = v; lidx = cb + c; }
        }
    }
    unsigned long long removed = 0ull;           // removal mask for OWN chunk
    int sel_reg = 0x7FFFFFFF;                    // lane i (<32) holds winner i
    for (int it = 0; it < KSEL; ++it) {
        float bv = lmax; int bi = lidx;
        #pragma unroll
        for (int off = 32; off; off >>= 1) {
            float ov = __shfl_xor(bv, off);
            int   oi = __shfl_xor(bi, off);
            if (ov > bv || (ov == bv && oi < bi)) { bv = ov; bi = oi; }
        }
        if (lane == it) sel_reg = bi;

        const int wl = bi >> 6;                  // winner chunk / owner lane
        if (lane == wl) removed |= (1ull << (bi & 63));

        unsigned long long rm = __shfl(removed, wl);
        float nv = vals[(wl << 6) + ((lane + wl) & 63)];
        int   ni = (wl << 6) + lane;
        if ((rm >> lane) & 1ull) nv = NEG_INF;
        #pragma unroll
        for (int off = 32; off; off >>= 1) {
            float ov = __shfl_xor(nv, off);
            int   oi = __shfl_xor(nv == nv ? ni : ni, off); // keep structure
            ov = __shfl_xor(nv, off);                        // (see below)
            oi = __shfl_xor(ni, off);
            if (ov > nv || (ov == nv && oi < ni)) { nv = ov; ni = oi; }
        }
        if (lane == wl) { lmax = nv; lidx = ni; }
    }
    // rank = ascending position (winners distinct)
    int myw = sel_reg;
    int rank = 0;
    #pragma unroll
    for (int j = 0; j < KSEL; ++j) {
        int wj = __shfl(sel_reg, j);
        rank += (wj < myw) ? 1 : 0;
    }
    if (lane < KSEL) idx_out[(size_t)r * KSEL + rank] = myw;
}

// ---------------------------------------------------------------------------
// Kernel 2: pure streaming one-hot fill. One block per output k-row
// (8*64*32 = 16384 blocks x 256 threads). Each thread writes 4 coalesced
// nontemporal float4; the single 1.0 is folded in via predication so no
// second store / no sync is needed. Structurally identical to a buffer
// fill -> should run at fill BW (~6 TB/s).
// ---------------------------------------------------------------------------
__global__ __launch_bounds__(256) void onehot_fill_kernel(
    const int* __restrict__ idx,        // (8*64*32)
    float* __restrict__ out)            // (8, 64, 32, 4096)
{
    const int row = blockIdx.x;         // ((b*64+m)*32 + k)
    const int tid = threadIdx.x;
    const int t   = idx[row];           // uniform -> scalar load + broadcast
    const int tq  = t >> 2;
    const int te  = t & 3;

    floatx4* orow = (floatx4*)(out + (size_t)row * NCOLS);
    #pragma unroll
    for (int c = 0; c < 4; ++c) {
        int q = (c << 8) + tid;         // float4 index, coalesced
        bool hit = (q == tq);
        floatx4 z;
        z.x = (hit && te == 0) ? 1.0f : 0.0f;
        z.y = (hit && te == 1) ? 1.0f : 0.0f;
        z.z = (hit && te == 2) ? 1.0f : 0.0f;
        z.w = (hit && te == 3) ? 1.0f : 0.0f;
        __builtin_nontemporal_store(z, orow + q);
    }
}

extern "C" void kernel_launch(void* const* d_in, const int* in_sizes, int n_in,
                              void* d_out, int out_size, void* d_ws, size_t ws_size,
                              hipStream_t stream) {
    const float* logits = (const float*)d_in[0];   // (64, 4096) fp32
    const float* u      = (const float*)d_in[1];   // (8, 64, 4096) fp32
    float* out          = (float*)d_out;           // (8, 64, 32, 4096) fp32
    int* idx            = (int*)d_ws;              // 64 KiB of workspace

    topk_select_kernel<<<BSZ * MROWS, 256, 0, stream>>>(logits, u, idx);
    onehot_fill_kernel<<<BSZ * MROWS * KSEL, 256, 0, stream>>>(idx, out);
}